// Round 15
// baseline (491.699 us; speedup 1.0000x reference)
//
#include <hip/hip_runtime.h>
#include <math.h>

#define TT 64
#define BB 64
#define DD 512
#define HH 512
#define G4 2048
#define OO 128

typedef unsigned short us16;
typedef __attribute__((ext_vector_type(8))) short bf16x8;
typedef __attribute__((ext_vector_type(4))) float f32x4;
typedef __attribute__((ext_vector_type(4))) unsigned u32x4;

__device__ __forceinline__ unsigned pk_bf16(float lo, float hi) {
  unsigned r;
  asm volatile("v_cvt_pk_bf16_f32 %0, %1, %2" : "=v"(r) : "v"(lo), "v"(hi));
  return r;
}

// fast gate math (bf16 tolerance is ample)
__device__ __forceinline__ float fsigm(float v) { return 1.f / (1.f + __expf(-v)); }
__device__ __forceinline__ float ftanh(float v) { return 1.f - 2.f / (__expf(2.f * v) + 1.f); }

// coherent (LLC-direct) accesses for cross-block data
__device__ __forceinline__ u32x4 load_b128_cc(const void* p) {
  u32x4 r;
  asm volatile("global_load_dwordx4 %0, %1, off sc0 sc1" : "=v"(r) : "v"(p));
  return r;
}
__device__ __forceinline__ void store_b128_cc(void* p, u32x4 v) {
  asm volatile("global_store_dwordx4 %0, %1, off sc0 sc1" ::"v"(p), "v"(v) : "memory");
}
__device__ __forceinline__ void store_b32_cc(void* p, float vf) {
  unsigned v = __builtin_bit_cast(unsigned, vf);
  asm volatile("global_store_dword %0, %1, off sc0 sc1" ::"v"(p), "v"(v) : "memory");
}

// ============================================================================
// MERGED kernel, grid 1280 x 256, __launch_bounds__(256, 2):
//   blocks 0..1023  : phaseA role — G tile (t = bid>>4, j0 = (bid&15)*128).
//                     NEVER waits on anything -> always progresses/retires.
//                     G stores sc0/sc1 (LLC-visible cross-XCD), vmcnt(0),
//                     block barrier, then atomicAdd gcnt[t].
//   blocks 1024..1279: lstm role — EXACT round-10 protocol (measured 264 us)
//                     + barrier-carried G-gate on wave2.
// Deadlock-free at ANY occupancy: phaseA blocks are dispatched FIRST and have
// no dependencies; lstm blocks launch as phaseA retires. Worst case (1
// block/CU) degrades to sequential phaseA-then-lstm; with >=2 blocks/CU
// (guaranteed: LDS 52.6KB -> 3/CU, VGPR <= 256 via launch_bounds) the
// recurrence overlaps the remaining phaseA tiles.
// G-gate: wave2 polls gcnt (its vmcnt is empty there -> no W-stream drain);
// wave2 can't reach the next barrier until the gate passes, so wave0's
// prefG(t+1) after that barrier is covered. Publish path untouched.
// ============================================================================
__global__ __launch_bounds__(256, 2) void fused_lstm(
    const float* __restrict__ x, const float* __restrict__ wih,
    const float* __restrict__ bih, const float* __restrict__ bhh,
    const float* __restrict__ whh, float* __restrict__ Gb,
    const int* __restrict__ lengths, char* __restrict__ hb,
    float* __restrict__ hf, unsigned* __restrict__ gcnt) {
  __shared__ us16 xa[2][64][64];      // 16 KB (phaseA role)
  __shared__ us16 wbufA[2][128][64];  // 32 KB (phaseA role)
  __shared__ float gm[2][16][36];     // 4.6 KB (lstm role)

  const int tid = threadIdx.x, bid = blockIdx.x;
  const int wv = tid >> 6, lane = tid & 63;

  if (bid < 1024) {
    // ===================== phaseA role: G tile (t, j0) =====================
    const int t = bid >> 4;
    const int j0 = (bid & 15) * 128;
    const int wm = wv & 1, wn = wv >> 1;
    const float* xb = x + (size_t)t * (BB * DD);
    const float* wg = wih + (size_t)t * (G4 * DD) + (size_t)j0 * DD;

    float4 xr[2][2], wr[4][2];
    int xrow[2], xc[2], wrow[4], wc[4];
#pragma unroll
    for (int i = 0; i < 2; i++) { int cid = tid + i * 256; xrow[i] = cid >> 3; xc[i] = cid & 7; }
#pragma unroll
    for (int i = 0; i < 4; i++) { int cid = tid + i * 256; wrow[i] = cid >> 3; wc[i] = cid & 7; }

    auto loadx = [&](int k0) {
#pragma unroll
      for (int i = 0; i < 2; i++) {
        const float* p = xb + xrow[i] * DD + k0 + xc[i] * 8;
        xr[i][0] = *(const float4*)p; xr[i][1] = *(const float4*)(p + 4);
      }
    };
    auto loadw = [&](int k0) {
#pragma unroll
      for (int i = 0; i < 4; i++) {
        const float* p = wg + (size_t)wrow[i] * DD + k0 + wc[i] * 8;
        wr[i][0] = *(const float4*)p; wr[i][1] = *(const float4*)(p + 4);
      }
    };
    auto store = [&](int buf) {
#pragma unroll
      for (int i = 0; i < 2; i++) {
        uint4 u;
        u.x = pk_bf16(xr[i][0].x, xr[i][0].y); u.y = pk_bf16(xr[i][0].z, xr[i][0].w);
        u.z = pk_bf16(xr[i][1].x, xr[i][1].y); u.w = pk_bf16(xr[i][1].z, xr[i][1].w);
        int p = xc[i] ^ (xrow[i] & 7);
        *(uint4*)&xa[buf][xrow[i]][p * 8] = u;
      }
#pragma unroll
      for (int i = 0; i < 4; i++) {
        uint4 u;
        u.x = pk_bf16(wr[i][0].x, wr[i][0].y); u.y = pk_bf16(wr[i][0].z, wr[i][0].w);
        u.z = pk_bf16(wr[i][1].x, wr[i][1].y); u.w = pk_bf16(wr[i][1].z, wr[i][1].w);
        int p = wc[i] ^ (wrow[i] & 7);
        *(uint4*)&wbufA[buf][wrow[i]][p * 8] = u;
      }
    };

    loadx(0); loadw(0); store(0);
    __syncthreads();

    f32x4 zero = {0.f, 0.f, 0.f, 0.f};
    f32x4 acc[2][4];
#pragma unroll
    for (int mt = 0; mt < 2; mt++)
#pragma unroll
      for (int nt = 0; nt < 4; nt++) acc[mt][nt] = zero;

    for (int s = 0; s < 8; s++) {
      const int nb = s & 1;
      if (s < 7) { loadx((s + 1) * 64); loadw((s + 1) * 64); }
#pragma unroll
      for (int ks = 0; ks < 2; ks++) {
        const int cc = ks * 4 + (lane >> 4);
        bf16x8 a[2], b[4];
#pragma unroll
        for (int mt = 0; mt < 2; mt++) {
          int r = wm * 32 + mt * 16 + (lane & 15);
          a[mt] = *(const bf16x8*)&xa[nb][r][(cc ^ (r & 7)) * 8];
        }
#pragma unroll
        for (int nt = 0; nt < 4; nt++) {
          int r = wn * 64 + nt * 16 + (lane & 15);
          b[nt] = *(const bf16x8*)&wbufA[nb][r][(cc ^ (r & 7)) * 8];
        }
#pragma unroll
        for (int mt = 0; mt < 2; mt++)
#pragma unroll
          for (int nt = 0; nt < 4; nt++)
            acc[mt][nt] = __builtin_amdgcn_mfma_f32_16x16x32_bf16(a[mt], b[nt], acc[mt][nt], 0, 0, 0);
      }
      __syncthreads();
      if (s < 7) store(nb ^ 1);
      __syncthreads();
    }

    float bias[4]; int jn[4];
#pragma unroll
    for (int nt = 0; nt < 4; nt++) {
      jn[nt] = j0 + wn * 64 + nt * 16 + (lane & 15);
      bias[nt] = bih[t * G4 + jn[nt]] + bhh[t * G4 + jn[nt]];
    }
#pragma unroll
    for (int mt = 0; mt < 2; mt++)
#pragma unroll
      for (int nt = 0; nt < 4; nt++)
#pragma unroll
        for (int e = 0; e < 4; e++) {
          int brow = wm * 32 + mt * 16 + (lane >> 4) * 4 + e;
          store_b32_cc(&Gb[((size_t)t * BB + brow) * G4 + jn[nt]], acc[mt][nt][e] + bias[nt]);
        }
    asm volatile("s_waitcnt vmcnt(0)" ::: "memory");  // G stores at LLC
    __syncthreads();                                  // whole block done
    if (tid == 0)
      __hip_atomic_fetch_add(&gcnt[t], 1u, __ATOMIC_RELAXED, __HIP_MEMORY_SCOPE_AGENT);
    return;
  }

  // ======================= lstm role (round-10 exact) ======================
  const int lbid = bid - 1024;
  const int bh = lbid & 1, ug = lbid >> 1;
  const int wm = wv & 1, kq = wv >> 1;
  const int l15 = lane & 15, klg = lane >> 4;

  const size_t jrow = (size_t)((l15 >> 2) * 512 + ug * 4 + (l15 & 3));

  float4 pf[8][2];
  auto prefW = [&](int tt) {
    const float* wt = whh + (size_t)tt * (G4 * HH) + jrow * HH;
#pragma unroll
    for (int s = 0; s < 8; s++) {
      const float* p = wt + (size_t)(kq * 32 + s * 4 + klg) * 8;
      pf[s][0] = *(const float4*)p;
      pf[s][1] = *(const float4*)(p + 4);
    }
  };
  bf16x8 wfrag[8];
  auto cvtW = [&]() {
#pragma unroll
    for (int s = 0; s < 8; s++) {
      uint4 u;
      u.x = pk_bf16(pf[s][0].x, pf[s][0].y); u.y = pk_bf16(pf[s][0].z, pf[s][0].w);
      u.z = pk_bf16(pf[s][1].x, pf[s][1].y); u.w = pk_bf16(pf[s][1].z, pf[s][1].w);
      wfrag[s] = __builtin_bit_cast(bf16x8, u);
    }
  };

  float2 gpre[4];
  auto prefG = [&](int tt) {
    if (wv == 0) {
      const float* gbp =
          Gb + ((size_t)tt * BB + bh * 32 + (lane & 31)) * G4 + ug * 4 + ((lane >> 5) << 1);
#pragma unroll
      for (int q = 0; q < 4; q++) gpre[q] = *(const float2*)(gbp + q * 512);
    }
  };
  auto gate = [&](int tt) {  // wait for phaseA cohort tt (16 tiles)
    while (__hip_atomic_load(&gcnt[tt], __ATOMIC_RELAXED, __HIP_MEMORY_SCOPE_AGENT) < 16u)
      __builtin_amdgcn_s_sleep(8);
  };

  const size_t cbase =
      (size_t)bh * 65536 + ((size_t)(kq * 64 + klg * 2) * 32 + wm * 16 + l15) * 16;
  const size_t pbase = (size_t)bh * 65536 + ((size_t)ug * 32 + (lane & 31)) * 16;

  const int mylen = (wv == 0) ? lengths[bh * 32 + (lane & 31)] : -2;
  float cst[2] = {0.f, 0.f};

  prefW(0);
  if (wv == 2) { gate(0); gate(1); }  // covers prefG(0) below and prefG(1) at t=0
  __syncthreads();
  prefG(0);

  for (int t = 0; t < TT; t++) {
    cvtW();  // consume pf (drains W loads)

    u32x4 r0[8], r1[8];
    if (t == 0) {
      u32x4 z = {0u, 0u, 0u, 0u};
#pragma unroll
      for (int s = 0; s < 8; s++) { r0[s] = z; r1[s] = z; }
    } else {
      const char* sbase = hb + (size_t)(t & 1) * 131072 + cbase;
      const unsigned tg = (unsigned)t;
      bool ok;
      do {
#pragma unroll
        for (int s = 0; s < 8; s++) {
          r0[s] = load_b128_cc(sbase + (size_t)s * 4096);
          r1[s] = load_b128_cc(sbase + (size_t)s * 4096 + 512);
        }
        asm volatile("s_waitcnt vmcnt(0)" ::: "memory");
        __builtin_amdgcn_sched_barrier(0);
        ok = true;
#pragma unroll
        for (int s = 0; s < 8; s++) ok = ok && (r0[s].z == tg) && (r1[s].z == tg);
        if (!__all(ok)) {
          __builtin_amdgcn_s_sleep(1);
          ok = false;
        } else {
          ok = true;
        }
      } while (!ok);
    }

    f32x4 acc = {0.f, 0.f, 0.f, 0.f};
#pragma unroll
    for (int s = 0; s < 8; s++) {
      u32x4 fa;
      fa.x = r0[s].x; fa.y = r0[s].y; fa.z = r1[s].x; fa.w = r1[s].y;
      acc = __builtin_amdgcn_mfma_f32_16x16x32_bf16(__builtin_bit_cast(bf16x8, fa),
                                                    wfrag[s], acc, 0, 0, 0);
    }
    *(f32x4*)&gm[kq][l15][wm * 16 + klg * 4] = acc;

    __syncthreads();

    float2 gcur[4];
    if (wv == 0) {
#pragma unroll
      for (int q = 0; q < 4; q++) gcur[q] = gpre[q];
    }
    // barrier-carried gate (wave2's vmcnt is empty here: poll drained it, and
    // its prefW(t+1) is issued only after this gate) — guarantees cohort t+2
    // complete before any wave can issue prefG(t+2) after the NEXT barrier.
    if (wv == 2 && t + 2 < TT) gate(t + 2);
    if (t + 1 < TT) { prefW(t + 1); prefG(t + 1); }

    if (wv == 0) {
      const int b = lane & 31, hi = lane >> 5;
      float hv[2];
#pragma unroll
      for (int uu = 0; uu < 2; uu++) {
        const int lu = hi * 2 + uu;
        float vi = (uu ? gcur[0].y : gcur[0].x) + gm[0][0 + lu][b] + gm[1][0 + lu][b];
        float vf = (uu ? gcur[1].y : gcur[1].x) + gm[0][4 + lu][b] + gm[1][4 + lu][b];
        float vg = (uu ? gcur[2].y : gcur[2].x) + gm[0][8 + lu][b] + gm[1][8 + lu][b];
        float vo = (uu ? gcur[3].y : gcur[3].x) + gm[0][12 + lu][b] + gm[1][12 + lu][b];
        float cn = fsigm(vf) * cst[uu] + fsigm(vi) * ftanh(vg);
        cst[uu] = cn;
        hv[uu] = fsigm(vo) * ftanh(cn);
      }
      // publish FIRST (cross-block critical path), hf store after
      unsigned hw = pk_bf16(hv[0], hv[1]);
      unsigned other = __shfl_xor(hw, 32);
      if (hi == 0 && t + 1 < TT) {
        u32x4 rec;
        rec.x = hw; rec.y = other; rec.z = (unsigned)(t + 1); rec.w = 0u;
        store_b128_cc(hb + (size_t)((t + 1) & 1) * 131072 + pbase, rec);
      }
      if (mylen - 1 == t) {
        float2 o2; o2.x = hv[0]; o2.y = hv[1];
        *(float2*)&hf[(size_t)(bh * 32 + b) * HH + ug * 4 + hi * 2] = o2;
      }
    }
  }
}

// ============================================================================
// Final: logits = hf @ w_ho^T + b_ho, then log_softmax
// ============================================================================
__global__ __launch_bounds__(128) void finalK(const float* __restrict__ hf,
                                              const float* __restrict__ who,
                                              const float* __restrict__ bho,
                                              float* __restrict__ out) {
  int b = blockIdx.x, o = threadIdx.x;
  const float* h = hf + b * HH;
  const float* w = who + o * HH;
  float s = bho[o];
#pragma unroll 4
  for (int k = 0; k < HH; k += 4) {
    float4 hv = *(const float4*)(h + k);
    float4 wv = *(const float4*)(w + k);
    s += hv.x * wv.x + hv.y * wv.y + hv.z * wv.z + hv.w * wv.w;
  }
  __shared__ float red[2];
  __shared__ float red2[2];
  float m = s;
#pragma unroll
  for (int msk = 32; msk; msk >>= 1) m = fmaxf(m, __shfl_xor(m, msk));
  int wave = o >> 6;
  if ((o & 63) == 0) red[wave] = m;
  __syncthreads();
  m = fmaxf(red[0], red[1]);
  float e = expf(s - m);
#pragma unroll
  for (int msk = 32; msk; msk >>= 1) e += __shfl_xor(e, msk);
  if ((o & 63) == 0) red2[wave] = e;
  __syncthreads();
  float sum = red2[0] + red2[1];
  out[b * OO + o] = (s - m) - logf(sum);
}

extern "C" void kernel_launch(void* const* d_in, const int* in_sizes, int n_in,
                              void* d_out, int out_size, void* d_ws, size_t ws_size,
                              hipStream_t stream) {
  const float* x = (const float*)d_in[0];
  const float* wih = (const float*)d_in[1];
  const float* whh = (const float*)d_in[2];
  const float* bih = (const float*)d_in[3];
  const float* bhh = (const float*)d_in[4];
  const float* who = (const float*)d_in[5];
  const float* bho = (const float*)d_in[6];
  const int* lengths = (const int*)d_in[7];
  float* out = (float*)d_out;

  char* ws = (char*)d_ws;
  float* Gb = (float*)ws;                                // 33,554,432 B
  char* hb = ws + 33554432;                              // 262,144 B (tagged h records)
  unsigned* gcnt = (unsigned*)(ws + 33554432 + 262144);  // 256 B (64 counters)
  float* hf = (float*)(ws + 33554432 + 262400);          // 131,072 B

  (void)hipMemsetAsync(hb, 0, 262400, stream);  // clear tags + gcnt (replay safety)

  fused_lstm<<<1280, 256, 0, stream>>>(x, wih, bih, bhh, whh, Gb, lengths, hb, hf, gcnt);
  finalK<<<BB, 128, 0, stream>>>(hf, who, bho, out);
}

// Round 16
// 378.056 us; speedup vs baseline: 1.3006x; 1.3006x over previous
//
#include <hip/hip_runtime.h>
#include <math.h>

#define TT 64
#define BB 64
#define DD 512
#define HH 512
#define G4 2048
#define OO 128

typedef unsigned short us16;
typedef __attribute__((ext_vector_type(8))) short bf16x8;
typedef __attribute__((ext_vector_type(4))) float f32x4;
typedef __attribute__((ext_vector_type(4))) unsigned u32x4;

__device__ __forceinline__ unsigned pk_bf16(float lo, float hi) {
  unsigned r;
  asm volatile("v_cvt_pk_bf16_f32 %0, %1, %2" : "=v"(r) : "v"(lo), "v"(hi));
  return r;
}

// fast gate math (bf16 tolerance is ample)
__device__ __forceinline__ float fsigm(float v) { return 1.f / (1.f + __expf(-v)); }
__device__ __forceinline__ float ftanh(float v) { return 1.f - 2.f / (__expf(2.f * v) + 1.f); }

// coherent (LLC-direct) accesses for cross-block data
__device__ __forceinline__ u32x4 load_b128_cc(const void* p) {
  u32x4 r;
  asm volatile("global_load_dwordx4 %0, %1, off sc0 sc1" : "=v"(r) : "v"(p));
  return r;
}
__device__ __forceinline__ unsigned load_b32_cc(const void* p) {
  unsigned r;
  asm volatile("global_load_dword %0, %1, off sc0 sc1" : "=v"(r) : "v"(p));
  return r;
}
__device__ __forceinline__ void store_b128_cc(void* p, u32x4 v) {
  asm volatile("global_store_dwordx4 %0, %1, off sc0 sc1" ::"v"(p), "v"(v) : "memory");
}

// ============================================================================
// Phase A: G[t,b,j] = x_t @ Wih_t^T + b_ih + b_hh   via bf16 MFMA  (r10 exact)
// ============================================================================
__global__ __launch_bounds__(256) void phaseA_mfma(
    const float* __restrict__ x, const float* __restrict__ wih,
    const float* __restrict__ bih, const float* __restrict__ bhh,
    float* __restrict__ Gb) {
  __shared__ us16 xa[2][64][64];
  __shared__ us16 wbuf[2][128][64];
  const int tid = threadIdx.x;
  const int t = blockIdx.y;
  const int j0 = blockIdx.x * 128;
  const int wv = tid >> 6, lane = tid & 63;
  const int wm = wv & 1, wn = wv >> 1;
  const float* xb = x + (size_t)t * (BB * DD);
  const float* wg = wih + (size_t)t * (G4 * DD) + (size_t)j0 * DD;

  float4 xr[2][2], wr[4][2];
  int xrow[2], xc[2], wrow[4], wc[4];
#pragma unroll
  for (int i = 0; i < 2; i++) { int cid = tid + i * 256; xrow[i] = cid >> 3; xc[i] = cid & 7; }
#pragma unroll
  for (int i = 0; i < 4; i++) { int cid = tid + i * 256; wrow[i] = cid >> 3; wc[i] = cid & 7; }

  auto loadx = [&](int k0) {
#pragma unroll
    for (int i = 0; i < 2; i++) {
      const float* p = xb + xrow[i] * DD + k0 + xc[i] * 8;
      xr[i][0] = *(const float4*)p; xr[i][1] = *(const float4*)(p + 4);
    }
  };
  auto loadw = [&](int k0) {
#pragma unroll
    for (int i = 0; i < 4; i++) {
      const float* p = wg + (size_t)wrow[i] * DD + k0 + wc[i] * 8;
      wr[i][0] = *(const float4*)p; wr[i][1] = *(const float4*)(p + 4);
    }
  };
  auto store = [&](int buf) {
#pragma unroll
    for (int i = 0; i < 2; i++) {
      uint4 u;
      u.x = pk_bf16(xr[i][0].x, xr[i][0].y); u.y = pk_bf16(xr[i][0].z, xr[i][0].w);
      u.z = pk_bf16(xr[i][1].x, xr[i][1].y); u.w = pk_bf16(xr[i][1].z, xr[i][1].w);
      int p = xc[i] ^ (xrow[i] & 7);
      *(uint4*)&xa[buf][xrow[i]][p * 8] = u;
    }
#pragma unroll
    for (int i = 0; i < 4; i++) {
      uint4 u;
      u.x = pk_bf16(wr[i][0].x, wr[i][0].y); u.y = pk_bf16(wr[i][0].z, wr[i][0].w);
      u.z = pk_bf16(wr[i][1].x, wr[i][1].y); u.w = pk_bf16(wr[i][1].z, wr[i][1].w);
      int p = wc[i] ^ (wrow[i] & 7);
      *(uint4*)&wbuf[buf][wrow[i]][p * 8] = u;
    }
  };

  loadx(0); loadw(0); store(0);
  __syncthreads();

  f32x4 zero = {0.f, 0.f, 0.f, 0.f};
  f32x4 acc[2][4];
#pragma unroll
  for (int mt = 0; mt < 2; mt++)
#pragma unroll
    for (int nt = 0; nt < 4; nt++) acc[mt][nt] = zero;

  for (int s = 0; s < 8; s++) {
    const int nb = s & 1;
    if (s < 7) { loadx((s + 1) * 64); loadw((s + 1) * 64); }
#pragma unroll
    for (int ks = 0; ks < 2; ks++) {
      const int cc = ks * 4 + (lane >> 4);
      bf16x8 a[2], b[4];
#pragma unroll
      for (int mt = 0; mt < 2; mt++) {
        int r = wm * 32 + mt * 16 + (lane & 15);
        a[mt] = *(const bf16x8*)&xa[nb][r][(cc ^ (r & 7)) * 8];
      }
#pragma unroll
      for (int nt = 0; nt < 4; nt++) {
        int r = wn * 64 + nt * 16 + (lane & 15);
        b[nt] = *(const bf16x8*)&wbuf[nb][r][(cc ^ (r & 7)) * 8];
      }
#pragma unroll
      for (int mt = 0; mt < 2; mt++)
#pragma unroll
        for (int nt = 0; nt < 4; nt++)
          acc[mt][nt] = __builtin_amdgcn_mfma_f32_16x16x32_bf16(a[mt], b[nt], acc[mt][nt], 0, 0, 0);
    }
    __syncthreads();
    if (s < 7) store(nb ^ 1);
    __syncthreads();
  }

  float bias[4]; int jn[4];
#pragma unroll
  for (int nt = 0; nt < 4; nt++) {
    jn[nt] = j0 + wn * 64 + nt * 16 + (lane & 15);
    bias[nt] = bih[t * G4 + jn[nt]] + bhh[t * G4 + jn[nt]];
  }
#pragma unroll
  for (int mt = 0; mt < 2; mt++)
#pragma unroll
    for (int nt = 0; nt < 4; nt++)
#pragma unroll
      for (int e = 0; e < 4; e++) {
        int brow = wm * 32 + mt * 16 + (lane >> 4) * 4 + e;
        Gb[((size_t)t * BB + brow) * G4 + jn[nt]] = acc[mt][nt][e] + bias[nt];
      }
}

// ============================================================================
// Persistent LSTM stepper — r10 champion + TWO-PHASE POLL (consumer-only).
// 256 blocks (bh = bid&1, ug = bid>>1 -> units ug*4..+3), 4 waves
// (wm = wv&1 -> batch-16-half, kq = wv>>1 -> k-256-half).
// h in global as 16B TAGGED RECORDS [8B = 4 bf16 h][4B tag][pad], 2-slot
// ping-pong, sc0/sc1 only. Publish = the data store; r10 publish path intact.
// Poll change: phase 1 spins on a SAMPLED tag set (2 dword loads/lane covering
// all 128 producers of this half — 64x fewer LLC requests per sweep than the
// full data sweep); phase 2 is the r10 data-carrying sweep with full
// per-record tag verification (correctness identical; phase 1 is just a gate).
// ============================================================================
__global__ __launch_bounds__(256, 1) void lstm_persist(
    const float* __restrict__ whh, const float* __restrict__ Gb,
    const int* __restrict__ lengths, char* __restrict__ hb,
    float* __restrict__ hf) {
  __shared__ float gm[2][16][36];

  const int tid = threadIdx.x, bid = blockIdx.x;
  const int bh = bid & 1, ug = bid >> 1;
  const int wv = tid >> 6, lane = tid & 63;
  const int wm = wv & 1, kq = wv >> 1;
  const int l15 = lane & 15, klg = lane >> 4;

  // B-fragment source row in Whh: ri = l15 -> gate q = ri>>2, unit u = ri&3
  const size_t jrow = (size_t)((l15 >> 2) * 512 + ug * 4 + (l15 & 3));

  float4 pf[8][2];  // W(t) fp32 prefetch
  auto prefW = [&](int tt) {
    const float* wt = whh + (size_t)tt * (G4 * HH) + jrow * HH;
#pragma unroll
    for (int s = 0; s < 8; s++) {
      const float* p = wt + (size_t)(kq * 32 + s * 4 + klg) * 8;
      pf[s][0] = *(const float4*)p;
      pf[s][1] = *(const float4*)(p + 4);
    }
  };
  bf16x8 wfrag[8];
  auto cvtW = [&]() {
#pragma unroll
    for (int s = 0; s < 8; s++) {
      uint4 u;
      u.x = pk_bf16(pf[s][0].x, pf[s][0].y); u.y = pk_bf16(pf[s][0].z, pf[s][0].w);
      u.z = pk_bf16(pf[s][1].x, pf[s][1].y); u.w = pk_bf16(pf[s][1].z, pf[s][1].w);
      wfrag[s] = __builtin_bit_cast(bf16x8, u);
    }
  };

  float2 gpre[4];  // Gb prefetch (wave0, 64 lanes: 2 units each)
  auto prefG = [&](int tt) {
    if (wv == 0) {
      const float* gbp =
          Gb + ((size_t)tt * BB + bh * 32 + (lane & 31)) * G4 + ug * 4 + ((lane >> 5) << 1);
#pragma unroll
      for (int q = 0; q < 4; q++) gpre[q] = *(const float2*)(gbp + q * 512);
    }
  };

  // consumer record base: record (u4, m) at half_base + (u4*32 + m)*16
  const size_t cbase =
      (size_t)bh * 65536 + ((size_t)(kq * 64 + klg * 2) * 32 + wm * 16 + l15) * 16;
  // producer (wave0, lanes 0..31): u4 = ug, m = lane
  const size_t pbase = (size_t)bh * 65536 + ((size_t)ug * 32 + (lane & 31)) * 16;
  // sampled-tag addresses: producers u4 = lane and lane+64, arbitrary m, +8 = tag
  const size_t tbase0 = (size_t)bh * 65536 + ((size_t)lane * 32 + l15) * 16 + 8;
  const size_t tbase1 = (size_t)bh * 65536 + ((size_t)(lane + 64) * 32 + 16 + l15) * 16 + 8;

  const int mylen = (wv == 0) ? lengths[bh * 32 + (lane & 31)] : -2;
  float cst[2] = {0.f, 0.f};  // c state in registers (wave0 lanes, 2 units each)

  prefW(0);
  prefG(0);

  for (int t = 0; t < TT; t++) {
    cvtW();  // consume pf (drains W loads)

    u32x4 r0[8], r1[8];
    if (t == 0) {
      u32x4 z = {0u, 0u, 0u, 0u};
#pragma unroll
      for (int s = 0; s < 8; s++) { r0[s] = z; r1[s] = z; }
    } else {
      const char* hslot = hb + (size_t)(t & 1) * 131072;
      const unsigned tg = (unsigned)t;
      // ---- phase 1: cheap sampled-tag spin (128 requests/wave/sweep) ----
      while (true) {
        unsigned f0 = load_b32_cc(hslot + tbase0);
        unsigned f1 = load_b32_cc(hslot + tbase1);
        asm volatile("s_waitcnt vmcnt(0)" ::: "memory");
        if (__all(f0 == tg && f1 == tg)) break;
        __builtin_amdgcn_s_sleep(2);
      }
      // ---- phase 2: data-carrying sweep, full verification (r10 exact) ----
      const char* sbase = hslot + cbase;
      bool ok;
      do {
#pragma unroll
        for (int s = 0; s < 8; s++) {
          r0[s] = load_b128_cc(sbase + (size_t)s * 4096);
          r1[s] = load_b128_cc(sbase + (size_t)s * 4096 + 512);
        }
        asm volatile("s_waitcnt vmcnt(0)" ::: "memory");
        __builtin_amdgcn_sched_barrier(0);
        ok = true;
#pragma unroll
        for (int s = 0; s < 8; s++) ok = ok && (r0[s].z == tg) && (r1[s].z == tg);
        if (!__all(ok)) {
          __builtin_amdgcn_s_sleep(1);
          ok = false;
        } else {
          ok = true;
        }
      } while (!ok);
    }

    f32x4 acc = {0.f, 0.f, 0.f, 0.f};
#pragma unroll
    for (int s = 0; s < 8; s++) {
      u32x4 fa;
      fa.x = r0[s].x; fa.y = r0[s].y; fa.z = r1[s].x; fa.w = r1[s].y;
      acc = __builtin_amdgcn_mfma_f32_16x16x32_bf16(__builtin_bit_cast(bf16x8, fa),
                                                    wfrag[s], acc, 0, 0, 0);
    }
    *(f32x4*)&gm[kq][l15][wm * 16 + klg * 4] = acc;

    __syncthreads();

    float2 gcur[4];
    if (wv == 0) {
#pragma unroll
      for (int q = 0; q < 4; q++) gcur[q] = gpre[q];
    }
    // W/G prefetch for t+1: streams during epilogue + next poll
    if (t + 1 < TT) { prefW(t + 1); prefG(t + 1); }

    if (wv == 0) {
      const int b = lane & 31, hi = lane >> 5;
      float hv[2];
#pragma unroll
      for (int uu = 0; uu < 2; uu++) {
        const int lu = hi * 2 + uu;
        float vi = (uu ? gcur[0].y : gcur[0].x) + gm[0][0 + lu][b] + gm[1][0 + lu][b];
        float vf = (uu ? gcur[1].y : gcur[1].x) + gm[0][4 + lu][b] + gm[1][4 + lu][b];
        float vg = (uu ? gcur[2].y : gcur[2].x) + gm[0][8 + lu][b] + gm[1][8 + lu][b];
        float vo = (uu ? gcur[3].y : gcur[3].x) + gm[0][12 + lu][b] + gm[1][12 + lu][b];
        float cn = fsigm(vf) * cst[uu] + fsigm(vi) * ftanh(vg);
        cst[uu] = cn;
        hv[uu] = fsigm(vo) * ftanh(cn);
      }
      // publish FIRST (cross-block critical path), hf store after
      unsigned hw = pk_bf16(hv[0], hv[1]);
      unsigned other = __shfl_xor(hw, 32);
      if (hi == 0 && t + 1 < TT) {
        u32x4 rec;
        rec.x = hw; rec.y = other; rec.z = (unsigned)(t + 1); rec.w = 0u;
        store_b128_cc(hb + (size_t)((t + 1) & 1) * 131072 + pbase, rec);
      }
      if (mylen - 1 == t) {
        float2 o2; o2.x = hv[0]; o2.y = hv[1];
        *(float2*)&hf[(size_t)(bh * 32 + b) * HH + ug * 4 + hi * 2] = o2;
      }
    }
  }
}

// ============================================================================
// Final: logits = hf @ w_ho^T + b_ho, then log_softmax
// ============================================================================
__global__ __launch_bounds__(128) void finalK(const float* __restrict__ hf,
                                              const float* __restrict__ who,
                                              const float* __restrict__ bho,
                                              float* __restrict__ out) {
  int b = blockIdx.x, o = threadIdx.x;
  const float* h = hf + b * HH;
  const float* w = who + o * HH;
  float s = bho[o];
#pragma unroll 4
  for (int k = 0; k < HH; k += 4) {
    float4 hv = *(const float4*)(h + k);
    float4 wv = *(const float4*)(w + k);
    s += hv.x * wv.x + hv.y * wv.y + hv.z * wv.z + hv.w * wv.w;
  }
  __shared__ float red[2];
  __shared__ float red2[2];
  float m = s;
#pragma unroll
  for (int msk = 32; msk; msk >>= 1) m = fmaxf(m, __shfl_xor(m, msk));
  int wave = o >> 6;
  if ((o & 63) == 0) red[wave] = m;
  __syncthreads();
  m = fmaxf(red[0], red[1]);
  float e = expf(s - m);
#pragma unroll
  for (int msk = 32; msk; msk >>= 1) e += __shfl_xor(e, msk);
  if ((o & 63) == 0) red2[wave] = e;
  __syncthreads();
  float sum = red2[0] + red2[1];
  out[b * OO + o] = (s - m) - logf(sum);
}

extern "C" void kernel_launch(void* const* d_in, const int* in_sizes, int n_in,
                              void* d_out, int out_size, void* d_ws, size_t ws_size,
                              hipStream_t stream) {
  const float* x = (const float*)d_in[0];
  const float* wih = (const float*)d_in[1];
  const float* whh = (const float*)d_in[2];
  const float* bih = (const float*)d_in[3];
  const float* bhh = (const float*)d_in[4];
  const float* who = (const float*)d_in[5];
  const float* bho = (const float*)d_in[6];
  const int* lengths = (const int*)d_in[7];
  float* out = (float*)d_out;

  char* ws = (char*)d_ws;
  float* Gb = (float*)ws;                        // 33,554,432 B
  char* hb = ws + 33554432;                      // 262,144 B (2 slots x 2 halves x 4096 records)
  float* hf = (float*)(ws + 33554432 + 262144);  // 131,072 B

  (void)hipMemsetAsync(hb, 0, 262144, stream);  // clear tags (graph-replay safety)

  phaseA_mfma<<<dim3(16, 64), 256, 0, stream>>>(x, wih, bih, bhh, Gb);
  lstm_persist<<<256, 256, 0, stream>>>(whh, Gb, lengths, hb, hf);
  finalK<<<BB, 128, 0, stream>>>(hf, who, bho, out);
}

// Round 17
// 376.568 us; speedup vs baseline: 1.3057x; 1.0040x over previous
//
#include <hip/hip_runtime.h>
#include <math.h>

#define TT 64
#define BB 64
#define DD 512
#define HH 512
#define G4 2048
#define OO 128

typedef unsigned short us16;
typedef __attribute__((ext_vector_type(8))) short bf16x8;
typedef __attribute__((ext_vector_type(4))) float f32x4;
typedef __attribute__((ext_vector_type(4))) unsigned u32x4;

__device__ __forceinline__ unsigned pk_bf16(float lo, float hi) {
  unsigned r;
  asm volatile("v_cvt_pk_bf16_f32 %0, %1, %2" : "=v"(r) : "v"(lo), "v"(hi));
  return r;
}

// fast gate math (bf16 tolerance is ample)
__device__ __forceinline__ float fsigm(float v) { return 1.f / (1.f + __expf(-v)); }
__device__ __forceinline__ float ftanh(float v) { return 1.f - 2.f / (__expf(2.f * v) + 1.f); }

// coherent (LLC-direct) accesses for cross-block data
__device__ __forceinline__ u32x4 load_b128_cc(const void* p) {
  u32x4 r;
  asm volatile("global_load_dwordx4 %0, %1, off sc0 sc1" : "=v"(r) : "v"(p));
  return r;
}
__device__ __forceinline__ void store_b32u_cc(void* p, unsigned v) {
  asm volatile("global_store_dword %0, %1, off sc0 sc1" ::"v"(p), "v"(v) : "memory");
}

// ============================================================================
// Phase A: G[t,b,j] = x_t @ Wih_t^T + b_ih + b_hh   via bf16 MFMA  (r10 exact)
// ============================================================================
__global__ __launch_bounds__(256) void phaseA_mfma(
    const float* __restrict__ x, const float* __restrict__ wih,
    const float* __restrict__ bih, const float* __restrict__ bhh,
    float* __restrict__ Gb) {
  __shared__ us16 xa[2][64][64];
  __shared__ us16 wbuf[2][128][64];
  const int tid = threadIdx.x;
  const int t = blockIdx.y;
  const int j0 = blockIdx.x * 128;
  const int wv = tid >> 6, lane = tid & 63;
  const int wm = wv & 1, wn = wv >> 1;
  const float* xb = x + (size_t)t * (BB * DD);
  const float* wg = wih + (size_t)t * (G4 * DD) + (size_t)j0 * DD;

  float4 xr[2][2], wr[4][2];
  int xrow[2], xc[2], wrow[4], wc[4];
#pragma unroll
  for (int i = 0; i < 2; i++) { int cid = tid + i * 256; xrow[i] = cid >> 3; xc[i] = cid & 7; }
#pragma unroll
  for (int i = 0; i < 4; i++) { int cid = tid + i * 256; wrow[i] = cid >> 3; wc[i] = cid & 7; }

  auto loadx = [&](int k0) {
#pragma unroll
    for (int i = 0; i < 2; i++) {
      const float* p = xb + xrow[i] * DD + k0 + xc[i] * 8;
      xr[i][0] = *(const float4*)p; xr[i][1] = *(const float4*)(p + 4);
    }
  };
  auto loadw = [&](int k0) {
#pragma unroll
    for (int i = 0; i < 4; i++) {
      const float* p = wg + (size_t)wrow[i] * DD + k0 + wc[i] * 8;
      wr[i][0] = *(const float4*)p; wr[i][1] = *(const float4*)(p + 4);
    }
  };
  auto store = [&](int buf) {
#pragma unroll
    for (int i = 0; i < 2; i++) {
      uint4 u;
      u.x = pk_bf16(xr[i][0].x, xr[i][0].y); u.y = pk_bf16(xr[i][0].z, xr[i][0].w);
      u.z = pk_bf16(xr[i][1].x, xr[i][1].y); u.w = pk_bf16(xr[i][1].z, xr[i][1].w);
      int p = xc[i] ^ (xrow[i] & 7);
      *(uint4*)&xa[buf][xrow[i]][p * 8] = u;
    }
#pragma unroll
    for (int i = 0; i < 4; i++) {
      uint4 u;
      u.x = pk_bf16(wr[i][0].x, wr[i][0].y); u.y = pk_bf16(wr[i][0].z, wr[i][0].w);
      u.z = pk_bf16(wr[i][1].x, wr[i][1].y); u.w = pk_bf16(wr[i][1].z, wr[i][1].w);
      int p = wc[i] ^ (wrow[i] & 7);
      *(uint4*)&wbuf[buf][wrow[i]][p * 8] = u;
    }
  };

  loadx(0); loadw(0); store(0);
  __syncthreads();

  f32x4 zero = {0.f, 0.f, 0.f, 0.f};
  f32x4 acc[2][4];
#pragma unroll
  for (int mt = 0; mt < 2; mt++)
#pragma unroll
    for (int nt = 0; nt < 4; nt++) acc[mt][nt] = zero;

  for (int s = 0; s < 8; s++) {
    const int nb = s & 1;
    if (s < 7) { loadx((s + 1) * 64); loadw((s + 1) * 64); }
#pragma unroll
    for (int ks = 0; ks < 2; ks++) {
      const int cc = ks * 4 + (lane >> 4);
      bf16x8 a[2], b[4];
#pragma unroll
      for (int mt = 0; mt < 2; mt++) {
        int r = wm * 32 + mt * 16 + (lane & 15);
        a[mt] = *(const bf16x8*)&xa[nb][r][(cc ^ (r & 7)) * 8];
      }
#pragma unroll
      for (int nt = 0; nt < 4; nt++) {
        int r = wn * 64 + nt * 16 + (lane & 15);
        b[nt] = *(const bf16x8*)&wbuf[nb][r][(cc ^ (r & 7)) * 8];
      }
#pragma unroll
      for (int mt = 0; mt < 2; mt++)
#pragma unroll
        for (int nt = 0; nt < 4; nt++)
          acc[mt][nt] = __builtin_amdgcn_mfma_f32_16x16x32_bf16(a[mt], b[nt], acc[mt][nt], 0, 0, 0);
    }
    __syncthreads();
    if (s < 7) store(nb ^ 1);
    __syncthreads();
  }

  float bias[4]; int jn[4];
#pragma unroll
  for (int nt = 0; nt < 4; nt++) {
    jn[nt] = j0 + wn * 64 + nt * 16 + (lane & 15);
    bias[nt] = bih[t * G4 + jn[nt]] + bhh[t * G4 + jn[nt]];
  }
#pragma unroll
  for (int mt = 0; mt < 2; mt++)
#pragma unroll
    for (int nt = 0; nt < 4; nt++)
#pragma unroll
      for (int e = 0; e < 4; e++) {
        int brow = wm * 32 + mt * 16 + (lane >> 4) * 4 + e;
        Gb[((size_t)t * BB + brow) * G4 + jn[nt]] = acc[mt][nt][e] + bias[nt];
      }
}

// ============================================================================
// Persistent LSTM stepper — r10 chain + TAG-IN-PAYLOAD records (half traffic).
// 256 blocks (bh = bid&1, ug = bid>>1 -> units ug*4..+3), 4 waves
// (wm = wv&1 -> batch-16-half, kq = wv>>1 -> k-256-half).
// h records: PURE 16B payload (8 bf16 = units 8c..8c+7 of batch m at
// chunk-major addr (c*32+m)*16). |h| <= 1 -> bit14 of every bf16 is 0, so
// bit14 carries a 1-bit epoch tag e(t) = (t>>1)&1 (consecutive uses of a
// ping-pong slot alternate it). Producers store their own 4B dword (atomic,
// tag OR'd in); consumers sweep 8 dwordx4/lane (was 16), verify per-dword
// tags, strip bit14, and feed the loads directly as MFMA A-fragments.
// Slot init: memset slot0=0x00, slot1=0x40 -> first use of each slot invalid.
// ============================================================================
__global__ __launch_bounds__(256, 1) void lstm_persist(
    const float* __restrict__ whh, const float* __restrict__ Gb,
    const int* __restrict__ lengths, char* __restrict__ hb,
    float* __restrict__ hf) {
  __shared__ float gm[2][16][36];

  const int tid = threadIdx.x, bid = blockIdx.x;
  const int bh = bid & 1, ug = bid >> 1;
  const int wv = tid >> 6, lane = tid & 63;
  const int wm = wv & 1, kq = wv >> 1;
  const int l15 = lane & 15, klg = lane >> 4;
  const unsigned M = 0x40004000u;

  // B-fragment source row in Whh: ri = l15 -> gate q = ri>>2, unit u = ri&3
  const size_t jrow = (size_t)((l15 >> 2) * 512 + ug * 4 + (l15 & 3));

  float4 pf[8][2];  // W(t) fp32 prefetch
  auto prefW = [&](int tt) {
    const float* wt = whh + (size_t)tt * (G4 * HH) + jrow * HH;
#pragma unroll
    for (int s = 0; s < 8; s++) {
      const float* p = wt + (size_t)(kq * 32 + s * 4 + klg) * 8;
      pf[s][0] = *(const float4*)p;
      pf[s][1] = *(const float4*)(p + 4);
    }
  };
  bf16x8 wfrag[8];
  auto cvtW = [&]() {
#pragma unroll
    for (int s = 0; s < 8; s++) {
      uint4 u;
      u.x = pk_bf16(pf[s][0].x, pf[s][0].y); u.y = pk_bf16(pf[s][0].z, pf[s][0].w);
      u.z = pk_bf16(pf[s][1].x, pf[s][1].y); u.w = pk_bf16(pf[s][1].z, pf[s][1].w);
      wfrag[s] = __builtin_bit_cast(bf16x8, u);
    }
  };

  float2 gpre[4];  // Gb prefetch (wave0, 64 lanes: 2 units each)
  auto prefG = [&](int tt) {
    if (wv == 0) {
      const float* gbp =
          Gb + ((size_t)tt * BB + bh * 32 + (lane & 31)) * G4 + ug * 4 + ((lane >> 5) << 1);
#pragma unroll
      for (int q = 0; q < 4; q++) gpre[q] = *(const float2*)(gbp + q * 512);
    }
  };

  // consumer: chunk c = kq*32 + s*4 + klg, batch m = wm*16 + l15;
  // addr = half + (c*32 + m)*16, s-stride 2048 B. Lanes contiguous in l15.
  const size_t cbase =
      (size_t)bh * 32768 + ((size_t)(kq * 32 + klg) * 32 + wm * 16 + l15) * 16;
  // producer (wave0, all 64 lanes): b = lane&31, hi = lane>>5 -> dword
  // d = ug*2 + hi -> chunk ug>>1, dword-in-chunk d&3.
  const size_t pbase = (size_t)bh * 32768 +
                       ((size_t)(ug >> 1) * 32 + (lane & 31)) * 16 +
                       (size_t)((ug * 2 + (lane >> 5)) & 3) * 4;

  const int mylen = (wv == 0) ? lengths[bh * 32 + (lane & 31)] : -2;
  float cst[2] = {0.f, 0.f};  // c state in registers (wave0 lanes, 2 units each)

  prefW(0);
  prefG(0);

  for (int t = 0; t < TT; t++) {
    cvtW();  // consume pf (drains W loads)

    u32x4 r[8];
    if (t == 0) {
      u32x4 z = {0u, 0u, 0u, 0u};
#pragma unroll
      for (int s = 0; s < 8; s++) r[s] = z;
    } else {
      const char* sbase = hb + (size_t)(t & 1) * 65536 + cbase;
      const unsigned tw = ((t >> 1) & 1) ? M : 0u;
      bool ok;
      do {
#pragma unroll
        for (int s = 0; s < 8; s++) r[s] = load_b128_cc(sbase + (size_t)s * 2048);
        asm volatile("s_waitcnt vmcnt(0)" ::: "memory");
        __builtin_amdgcn_sched_barrier(0);
        unsigned bad = 0u;
#pragma unroll
        for (int s = 0; s < 8; s++) {
          bad |= ((r[s].x & M) ^ tw) | ((r[s].y & M) ^ tw);
          bad |= ((r[s].z & M) ^ tw) | ((r[s].w & M) ^ tw);
        }
        if (!__all(bad == 0u)) {
          __builtin_amdgcn_s_sleep(1);
          ok = false;
        } else {
          ok = true;
        }
      } while (!ok);
#pragma unroll
      for (int s = 0; s < 8; s++) r[s] &= 0xBFFFBFFFu;  // strip tag bits
    }

    f32x4 acc = {0.f, 0.f, 0.f, 0.f};
#pragma unroll
    for (int s = 0; s < 8; s++)
      acc = __builtin_amdgcn_mfma_f32_16x16x32_bf16(__builtin_bit_cast(bf16x8, r[s]),
                                                    wfrag[s], acc, 0, 0, 0);
    *(f32x4*)&gm[kq][l15][wm * 16 + klg * 4] = acc;

    __syncthreads();

    float2 gcur[4];
    if (wv == 0) {
#pragma unroll
      for (int q = 0; q < 4; q++) gcur[q] = gpre[q];
    }
    // W/G prefetch for t+1: streams during epilogue + next poll
    if (t + 1 < TT) { prefW(t + 1); prefG(t + 1); }

    if (wv == 0) {
      const int b = lane & 31, hi = lane >> 5;
      float hv[2];
#pragma unroll
      for (int uu = 0; uu < 2; uu++) {
        const int lu = hi * 2 + uu;
        float vi = (uu ? gcur[0].y : gcur[0].x) + gm[0][0 + lu][b] + gm[1][0 + lu][b];
        float vf = (uu ? gcur[1].y : gcur[1].x) + gm[0][4 + lu][b] + gm[1][4 + lu][b];
        float vg = (uu ? gcur[2].y : gcur[2].x) + gm[0][8 + lu][b] + gm[1][8 + lu][b];
        float vo = (uu ? gcur[3].y : gcur[3].x) + gm[0][12 + lu][b] + gm[1][12 + lu][b];
        float cn = fsigm(vf) * cst[uu] + fsigm(vi) * ftanh(vg);
        cst[uu] = cn;
        hv[uu] = fsigm(vo) * ftanh(cn);
      }
      // publish FIRST (cross-block critical path): one 4B dword per lane,
      // epoch tag in bit14 of each bf16 (genuine bit14s are always 0).
      if (t + 1 < TT) {
        unsigned tagb = (((t + 1) >> 1) & 1) ? M : 0u;
        unsigned hw = pk_bf16(hv[0], hv[1]) | tagb;
        store_b32u_cc(hb + (size_t)((t + 1) & 1) * 65536 + pbase, hw);
      }
      if (mylen - 1 == t) {
        float2 o2; o2.x = hv[0]; o2.y = hv[1];
        *(float2*)&hf[(size_t)(bh * 32 + b) * HH + ug * 4 + hi * 2] = o2;
      }
    }
  }
}

// ============================================================================
// Final: logits = hf @ w_ho^T + b_ho, then log_softmax
// ============================================================================
__global__ __launch_bounds__(128) void finalK(const float* __restrict__ hf,
                                              const float* __restrict__ who,
                                              const float* __restrict__ bho,
                                              float* __restrict__ out) {
  int b = blockIdx.x, o = threadIdx.x;
  const float* h = hf + b * HH;
  const float* w = who + o * HH;
  float s = bho[o];
#pragma unroll 4
  for (int k = 0; k < HH; k += 4) {
    float4 hv = *(const float4*)(h + k);
    float4 wv = *(const float4*)(w + k);
    s += hv.x * wv.x + hv.y * wv.y + hv.z * wv.z + hv.w * wv.w;
  }
  __shared__ float red[2];
  __shared__ float red2[2];
  float m = s;
#pragma unroll
  for (int msk = 32; msk; msk >>= 1) m = fmaxf(m, __shfl_xor(m, msk));
  int wave = o >> 6;
  if ((o & 63) == 0) red[wave] = m;
  __syncthreads();
  m = fmaxf(red[0], red[1]);
  float e = expf(s - m);
#pragma unroll
  for (int msk = 32; msk; msk >>= 1) e += __shfl_xor(e, msk);
  if ((o & 63) == 0) red2[wave] = e;
  __syncthreads();
  float sum = red2[0] + red2[1];
  out[b * OO + o] = (s - m) - logf(sum);
}

extern "C" void kernel_launch(void* const* d_in, const int* in_sizes, int n_in,
                              void* d_out, int out_size, void* d_ws, size_t ws_size,
                              hipStream_t stream) {
  const float* x = (const float*)d_in[0];
  const float* wih = (const float*)d_in[1];
  const float* whh = (const float*)d_in[2];
  const float* bih = (const float*)d_in[3];
  const float* bhh = (const float*)d_in[4];
  const float* who = (const float*)d_in[5];
  const float* bho = (const float*)d_in[6];
  const int* lengths = (const int*)d_in[7];
  float* out = (float*)d_out;

  char* ws = (char*)d_ws;
  float* Gb = (float*)ws;                        // 33,554,432 B
  char* hb = ws + 33554432;                      // 131,072 B (2 slots x 2 halves x 32 KB)
  float* hf = (float*)(ws + 33554432 + 131072);  // 131,072 B

  // slot0 -> tag bits 0 (invalid for its first use at t=2, e=1);
  // slot1 -> tag bits 1 (invalid for its first use at t=1, e=0).
  (void)hipMemsetAsync(hb, 0x00, 65536, stream);
  (void)hipMemsetAsync(hb + 65536, 0x40, 65536, stream);

  phaseA_mfma<<<dim3(16, 64), 256, 0, stream>>>(x, wih, bih, bhh, Gb);
  lstm_persist<<<256, 256, 0, stream>>>(whh, Gb, lengths, hb, hf);
  finalK<<<BB, 128, 0, stream>>>(hf, who, bho, out);
}